// Round 4
// baseline (568.561 us; speedup 1.0000x reference)
//
#include <hip/hip_runtime.h>
#include <hip/hip_bf16.h>

typedef __hip_bfloat16 bf16;
typedef __attribute__((ext_vector_type(4))) float  floatx4;
typedef __attribute__((ext_vector_type(8))) short  short8;
typedef __attribute__((ext_vector_type(8))) __bf16 bf16x8;

constexpr int Bc = 4, Lc = 1024, Sc = 1024, DIMc = 1024, NHc = 16, DHc = 64;

// ---- MFMA dispatcher: works whether the builtin takes short8 or bf16x8 ----
template <typename V>
__device__ auto mfma_bf16_sel(V a, V b, floatx4 c, int)
    -> decltype(__builtin_amdgcn_mfma_f32_16x16x32_bf16(a, b, c, 0, 0, 0)) {
  return __builtin_amdgcn_mfma_f32_16x16x32_bf16(a, b, c, 0, 0, 0);
}
template <typename V>
__device__ floatx4 mfma_bf16_sel(V a, V b, floatx4 c, long) {
  bf16x8 a2 = __builtin_bit_cast(bf16x8, a);
  bf16x8 b2 = __builtin_bit_cast(bf16x8, b);
  return __builtin_amdgcn_mfma_f32_16x16x32_bf16(a2, b2, c, 0, 0, 0);
}
__device__ inline floatx4 mfma_bf16(short8 a, short8 b, floatx4 c) {
  return mfma_bf16_sel(a, b, c, 0);
}

// ---- async global->LDS (16B per lane, wave-uniform LDS base + lane*16) ----
__device__ inline void gload16(const bf16* g, bf16* l) {
  __builtin_amdgcn_global_load_lds(
      (const __attribute__((address_space(1))) unsigned int*)g,
      (__attribute__((address_space(3))) unsigned int*)l, 16, 0, 0);
}

union U8 { uint4 u; bf16 h[8]; };

__device__ inline U8 load8cvt(const float* p) {
    float4 f0 = ((const float4*)p)[0];
    float4 f1 = ((const float4*)p)[1];
    U8 t;
    t.h[0] = __float2bfloat16(f0.x); t.h[1] = __float2bfloat16(f0.y);
    t.h[2] = __float2bfloat16(f0.z); t.h[3] = __float2bfloat16(f0.w);
    t.h[4] = __float2bfloat16(f1.x); t.h[5] = __float2bfloat16(f1.y);
    t.h[6] = __float2bfloat16(f1.z); t.h[7] = __float2bfloat16(f1.w);
    return t;
}

// ---------------------------------------------------------------------------
// Prep: blocks [0,6144): cast q,k,v fp32->bf16 (2048 elems/block).
//       blocks [6144,7168): transpose+cast weights into Wt[n][k] bf16.
//       blocks [7168,7424): bit-pack mask into mbits + rowany (causal-aware).
// ---------------------------------------------------------------------------
__global__ __launch_bounds__(256)
void prep_kernel(const float* __restrict__ q, const float* __restrict__ k,
                 const float* __restrict__ v,
                 const float* __restrict__ Wq, const float* __restrict__ Wk,
                 const float* __restrict__ Wv, const float* __restrict__ Wp,
                 const int* __restrict__ mask, const int* __restrict__ is_causal_p,
                 bf16* __restrict__ qb, bf16* __restrict__ kb,
                 bf16* __restrict__ vb,
                 bf16* __restrict__ wqt, bf16* __restrict__ wkt,
                 bf16* __restrict__ wvt, bf16* __restrict__ wpt,
                 unsigned long long* __restrict__ mbits,
                 int* __restrict__ rowany_g)
{
    __shared__ float tile[64][68];
    const int tid = threadIdx.x;
    int blk = blockIdx.x;

    if (blk < 6144) {
        const float* src = (blk < 2048) ? q : (blk < 4096) ? k : v;
        bf16*        dst = (blk < 2048) ? qb : (blk < 4096) ? kb : vb;
        const int off = (blk & 2047) * 2048 + tid * 8;
        U8 t = load8cvt(src + off);
        *(uint4*)(dst + off) = t.u;
    } else if (blk < 7168) {
        blk -= 6144;
        const int w  = blk >> 8, t2 = blk & 255;
        const float* W  = (w == 0) ? Wq : (w == 1) ? Wk : (w == 2) ? Wv : Wp;
        bf16*        Wt = (w == 0) ? wqt : (w == 1) ? wkt : (w == 2) ? wvt : wpt;
        const int tk = (t2 >> 4) << 6;   // k-tile base
        const int tn = (t2 & 15) << 6;   // n-tile base
        #pragma unroll
        for (int i = 0; i < 4; ++i) {
            const int r = (tid >> 4) + i * 16;   // 0..63 (k within tile)
            const int c = (tid & 15) << 2;       // 0..60 (n within tile)
            *(float4*)(&tile[r][c]) =
                *(const float4*)(W + (size_t)(tk + r) * DIMc + tn + c);
        }
        __syncthreads();
        #pragma unroll
        for (int j = 0; j < 2; ++j) {
            const int nn = tid >> 2;                  // 0..63
            const int kc = (tid & 3) + j * 4;         // 0..7
            U8 o;
            #pragma unroll
            for (int u = 0; u < 8; ++u)
                o.h[u] = __float2bfloat16(tile[kc * 8 + u][nn]);
            *(uint4*)(Wt + (size_t)(tn + nn) * DIMc + tk + kc * 8) = o.u;
        }
    } else {
        const int mb  = blk - 7168;          // 0..255
        const int rIb = tid >> 4;            // 0..15
        const int w   = tid & 15;            // 64-bit word within row
        const int row = mb * 16 + rIb;       // 0..4095  (b*1024 + l)
        const int l   = row & (Lc - 1);
        const bool causal = (is_causal_p[0] != 0);

        const int4* mr4 = (const int4*)(mask + (size_t)row * Sc + w * 64);
        unsigned long long bits = 0ull;
        #pragma unroll
        for (int i = 0; i < 16; ++i) {
            int4 m4 = mr4[i];
            unsigned long long nib =
                (unsigned long long)((m4.x != 0) | ((m4.y != 0) << 1) |
                                     ((m4.z != 0) << 2) | ((m4.w != 0) << 3));
            bits |= nib << (4 * i);
        }
        mbits[(size_t)row * 16 + w] = bits;

        const int limit = causal ? l : (Sc - 1);
        const int base  = w * 64;
        unsigned long long am;
        if (limit >= base + 63)  am = bits;
        else if (limit < base)   am = 0ull;
        else                     am = bits & ((2ull << (limit - base)) - 1ull);
        unsigned long long red = am;
        #pragma unroll
        for (int d2 = 1; d2 < 16; d2 <<= 1) red |= __shfl_xor(red, d2);
        if (w == 0) rowany_g[row] = (red != 0ull) ? 1 : 0;
    }
}

// ---------------------------------------------------------------------------
// m97-structure GEMM (B^T form): bf16 A and Bt, global_load_lds width-16
// staging into LINEAR LDS [128][64], BK=64, 4 waves 2x2, 4x4 MFMA per wave.
// Fused QKV via blockIdx.z. qh is pre-scaled by 0.125 (flash adds no scale).
// z<2 -> out[((b*NH+h)*L+l)*DH+d] ; z==2 -> out[((b*NH+h)*DH+d)*S+l]
// ---------------------------------------------------------------------------
__global__ __launch_bounds__(256)
void gemm_qkv_kernel(const bf16* __restrict__ qb, const bf16* __restrict__ kb,
                     const bf16* __restrict__ vb,
                     const bf16* __restrict__ wqt, const bf16* __restrict__ wkt,
                     const bf16* __restrict__ wvt,
                     const float* __restrict__ bq, const float* __restrict__ bk,
                     const float* __restrict__ bv,
                     bf16* __restrict__ qh, bf16* __restrict__ kh,
                     bf16* __restrict__ vt)
{
    __shared__ __align__(16) bf16 As[128 * 64];
    __shared__ __align__(16) bf16 Bs[128 * 64];

    const int z = blockIdx.z;
    const bf16*  A    = (z == 0) ? qb  : (z == 1) ? kb  : vb;
    const bf16*  Bt   = (z == 0) ? wqt : (z == 1) ? wkt : wvt;
    const float* bias = (z == 0) ? bq  : (z == 1) ? bk  : bv;
    bf16*        out  = (z == 0) ? qh  : (z == 1) ? kh  : vt;
    const float  scale = (z == 0) ? 0.125f : 1.0f;

    const int tid  = threadIdx.x;
    const int wave = tid >> 6;
    const int lane = tid & 63;
    const int n = lane & 15, g = lane >> 4;
    const int m0 = blockIdx.x * 128;
    const int n0 = blockIdx.y * 128;
    const int wq_m = (wave & 1) * 64, wq_n = (wave >> 1) * 64;

    const int lrow   = lane >> 3;     // 0..7
    const int lchunk = (lane & 7) * 8;

    floatx4 acc[4][4];
    #pragma unroll
    for (int a = 0; a < 4; ++a)
        #pragma unroll
        for (int b2 = 0; b2 < 4; ++b2)
            acc[a][b2] = (floatx4){0.f, 0.f, 0.f, 0.f};

    for (int k0 = 0; k0 < DIMc; k0 += 64) {
        #pragma unroll
        for (int j = 0; j < 4; ++j) {
            const int rbase = j * 32 + wave * 8;
            const int r = rbase + lrow;
            gload16(A  + (size_t)(m0 + r) * DIMc + k0 + lchunk, As + rbase * 64);
            gload16(Bt + (size_t)(n0 + r) * DIMc + k0 + lchunk, Bs + rbase * 64);
        }
        __syncthreads();
        #pragma unroll
        for (int ks = 0; ks < 2; ++ks) {
            short8 af[4], bf_[4];
            #pragma unroll
            for (int t = 0; t < 4; ++t) {
                af[t]  = *(const short8*)(&As[(wq_m + t * 16 + n) * 64 + ks * 32 + g * 8]);
                bf_[t] = *(const short8*)(&Bs[(wq_n + t * 16 + n) * 64 + ks * 32 + g * 8]);
            }
            #pragma unroll
            for (int tm = 0; tm < 4; ++tm)
                #pragma unroll
                for (int tn = 0; tn < 4; ++tn)
                    acc[tm][tn] = mfma_bf16(af[tm], bf_[tn], acc[tm][tn]);
        }
        __syncthreads();
    }

    // epilogue: C/D layout col = lane&15 (=n), row = g*4 + r
    #pragma unroll
    for (int tn = 0; tn < 4; ++tn) {
        const int col = n0 + wq_n + tn * 16 + n;
        const float bval = bias[col];
        #pragma unroll
        for (int tm = 0; tm < 4; ++tm) {
            #pragma unroll
            for (int r = 0; r < 4; ++r) {
                const int row = m0 + wq_m + tm * 16 + g * 4 + r;
                const float vv = (acc[tm][tn][r] + bval) * scale;
                const int bb = row >> 10, ll = row & (Lc - 1);
                const int hh = col >> 6,  dd = col & 63;
                size_t idx;
                if (z < 2) idx = (((size_t)(bb * NHc + hh) * Lc + ll) * DHc) + dd;
                else       idx = (((size_t)(bb * NHc + hh) * DHc + dd) * Sc) + ll;
                out[idx] = __float2bfloat16(vv);
            }
        }
    }
}

// ---------------------------------------------------------------------------
// Output-projection GEMM, m97 structure: A bf16, fp32 out, row-major.
// ---------------------------------------------------------------------------
__global__ __launch_bounds__(256)
void gemm_out_kernel(const bf16* __restrict__ A, const bf16* __restrict__ Bt,
                     const float* __restrict__ bias, float* __restrict__ out)
{
    __shared__ __align__(16) bf16 As[128 * 64];
    __shared__ __align__(16) bf16 Bs[128 * 64];

    const int tid  = threadIdx.x;
    const int wave = tid >> 6;
    const int lane = tid & 63;
    const int n = lane & 15, g = lane >> 4;
    const int m0 = blockIdx.x * 128;
    const int n0 = blockIdx.y * 128;
    const int wq_m = (wave & 1) * 64, wq_n = (wave >> 1) * 64;

    const int lrow   = lane >> 3;
    const int lchunk = (lane & 7) * 8;

    floatx4 acc[4][4];
    #pragma unroll
    for (int a = 0; a < 4; ++a)
        #pragma unroll
        for (int b2 = 0; b2 < 4; ++b2)
            acc[a][b2] = (floatx4){0.f, 0.f, 0.f, 0.f};

    for (int k0 = 0; k0 < DIMc; k0 += 64) {
        #pragma unroll
        for (int j = 0; j < 4; ++j) {
            const int rbase = j * 32 + wave * 8;
            const int r = rbase + lrow;
            gload16(A  + (size_t)(m0 + r) * DIMc + k0 + lchunk, As + rbase * 64);
            gload16(Bt + (size_t)(n0 + r) * DIMc + k0 + lchunk, Bs + rbase * 64);
        }
        __syncthreads();
        #pragma unroll
        for (int ks = 0; ks < 2; ++ks) {
            short8 af[4], bf_[4];
            #pragma unroll
            for (int t = 0; t < 4; ++t) {
                af[t]  = *(const short8*)(&As[(wq_m + t * 16 + n) * 64 + ks * 32 + g * 8]);
                bf_[t] = *(const short8*)(&Bs[(wq_n + t * 16 + n) * 64 + ks * 32 + g * 8]);
            }
            #pragma unroll
            for (int tm = 0; tm < 4; ++tm)
                #pragma unroll
                for (int tn = 0; tn < 4; ++tn)
                    acc[tm][tn] = mfma_bf16(af[tm], bf_[tn], acc[tm][tn]);
        }
        __syncthreads();
    }

    #pragma unroll
    for (int tn = 0; tn < 4; ++tn) {
        const int col = n0 + wq_n + tn * 16 + n;
        const float bval = bias[col];
        #pragma unroll
        for (int tm = 0; tm < 4; ++tm) {
            #pragma unroll
            for (int r = 0; r < 4; ++r) {
                const int row = m0 + wq_m + tm * 16 + g * 4 + r;
                out[(size_t)row * DIMc + col] = acc[tm][tn][r] + bval;
            }
        }
    }
}

// ---------------------------------------------------------------------------
// Flash MFMA attention, chunk-pipelined, single barrier per chunk.
//  - K LDS rows permuted: logical s-row stored at perm(s)=(s>>2)+16*(s&3),
//    so QK^T B-operand reads hit rows 16t+n (bank-conflict-free) while
//    score columns stay contiguous (s = s0+4n+t) for float4 bias loads.
//  - K/V double-buffered in LDS: compute on buf[cur] while regs for chunk
//    c+1 are written to buf[cur^1]; ONE barrier per chunk.
//  - bias folded into QK^T accumulator init (qh pre-scaled by 0.125).
//  - s_setprio(1) around MFMA clusters.
// ---------------------------------------------------------------------------
constexpr int PADk = 72;

__global__ __launch_bounds__(256)
void flash_attn_kernel(const bf16* __restrict__ qh, const bf16* __restrict__ kh,
                       const bf16* __restrict__ vt,
                       const unsigned long long* __restrict__ mbits,
                       const int* __restrict__ rowany_g,
                       const float* __restrict__ pos_bias,
                       const int* __restrict__ is_causal_p, bf16* __restrict__ o)
{
    __shared__ bf16 Ks[2][64 * PADk];
    __shared__ bf16 Vs[2][64 * PADk];
    __shared__ bf16 Pw[4][16 * PADk];
    __shared__ int rowany[64];
    __shared__ int hasfix_s;

    const int tid  = threadIdx.x;
    const int lane = tid & 63;
    const int wave = tid >> 6;
    const int n = lane & 15;
    const int g = lane >> 4;

    // heavy-first: qt descending in dispatch order
    const int qt = 15 - (blockIdx.x >> 6);
    const int bh = blockIdx.x & 63;
    const int h  = bh & (NHc - 1);
    const int b  = bh >> 4;
    const int l0 = qt * 64;
    const bool causal = (is_causal_p[0] != 0);

    if (tid == 0) hasfix_s = 0;
    __syncthreads();
    if (tid < 64) {
        const int ra = rowany_g[(b << 10) + l0 + tid];
        rowany[tid] = ra;
        if (ra == 0) atomicOr(&hasfix_s, 1);
    }
    __syncthreads();
    const bool hasfix = (hasfix_s != 0);

    const int qrow_frag = l0 + wave * 16 + n;
    const bf16* qp = qh + ((size_t)bh * Lc + qrow_frag) * DHc;
    const short8 qf0 = *(const short8*)(qp + g * 8);
    const short8 qf1 = *(const short8*)(qp + 32 + g * 8);

    // staging addresses.  K: logical row r stored at perm(r)=(r>>2)+16*(r&3)
    const int r0a = tid >> 3;            // 0..31
    const int c0  = (tid & 7) * 8;       // 0..56
    const int r0b = r0a + 32;            // 32..63
    const int pa_ = ((r0a >> 2) + ((r0a & 3) << 4));
    const int pb_ = ((r0b >> 2) + ((r0b & 3) << 4));
    const bf16* kb0p = kh + ((size_t)bh * Sc + r0a) * DHc + c0;
    const bf16* kb1p = kh + ((size_t)bh * Sc + r0b) * DHc + c0;
    const bf16* vb0p = vt + ((size_t)bh * DHc + r0a) * Sc + c0;
    const bf16* vb1p = vt + ((size_t)bh * DHc + r0b) * Sc + c0;
    const int kofsA = pa_ * PADk + c0;
    const int kofsB = pb_ * PADk + c0;
    const int vofsA = r0a * PADk + c0;
    const int vofsB = r0b * PADk + c0;

    // per-row bias / mask bases + row-constant predicates
    union F4 { float4 v; float f[4]; };
    const float* brow[4];
    const unsigned long long* mrow[4];
    int limit_r[4]; bool fix_r[4];
    #pragma unroll
    for (int r = 0; r < 4; ++r) {
        const int row = wave * 16 + g * 4 + r;
        const int l = l0 + row;
        brow[r] = pos_bias + ((size_t)bh * Lc + l) * Sc + 4 * n;
        mrow[r] = mbits + ((size_t)(b << 10) + l) * 16;
        limit_r[r] = causal ? l : (Sc - 1);
        fix_r[r] = (rowany[row] == 0);
    }

    floatx4 oacc[4];
    #pragma unroll
    for (int t = 0; t < 4; ++t) oacc[t] = (floatx4){0.f, 0.f, 0.f, 0.f};
    float m_run[4], l_run[4];
    #pragma unroll
    for (int r = 0; r < 4; ++r) { m_run[r] = -3.0e38f; l_run[r] = 0.f; }

    int nchunk = Sc / 64;
    if (causal && !hasfix) nchunk = qt + 1;

    // prologue: stage chunk 0 into buf 0
    {
        uint4 k0r = *(const uint4*)(kb0p);
        uint4 k1r = *(const uint4*)(kb1p);
        uint4 v0r = *(const uint4*)(vb0p);
        uint4 v1r = *(const uint4*)(vb1p);
        *(uint4*)(&Ks[0][kofsA]) = k0r;
        *(uint4*)(&Ks[0][kofsB]) = k1r;
        *(uint4*)(&Vs[0][vofsA]) = v0r;
        *(uint4*)(&Vs[0][vofsB]) = v1r;
    }
    F4 bcur[4], bnxt[4];
    unsigned long long mcur[4], mnxt[4];
    #pragma unroll
    for (int r = 0; r < 4; ++r) {
        bcur[r].v = *(const float4*)(brow[r]);
        mcur[r]   = mrow[r][0];
    }
    __syncthreads();

    uint4 kr0, kr1, vr0, vr1;
    for (int c = 0; c < nchunk; ++c) {
        const int cur = c & 1;
        const bool more = (c + 1 < nchunk);

        // issue global loads for chunk c+1 (latency hides under compute)
        if (more) {
            const size_t ko = (size_t)(c + 1) * (64 * DHc);
            const int    vo = (c + 1) * 64;
            kr0 = *(const uint4*)(kb0p + ko);
            kr1 = *(const uint4*)(kb1p + ko);
            vr0 = *(const uint4*)(vb0p + vo);
            vr1 = *(const uint4*)(vb1p + vo);
            #pragma unroll
            for (int r = 0; r < 4; ++r) {
                bnxt[r].v = *(const float4*)(brow[r] + vo);
                mnxt[r]   = mrow[r][c + 1];
            }
        }

        // QK^T with bias as accumulator init (qh pre-scaled by 0.125).
        // Physical row 16t+n holds logical K row 4n+t -> score col s0+4n+t.
        floatx4 scv[4];
        #pragma unroll
        for (int t = 0; t < 4; ++t)
            scv[t] = (floatx4){bcur[0].f[t], bcur[1].f[t],
                               bcur[2].f[t], bcur[3].f[t]};
        __builtin_amdgcn_s_setprio(1);
        #pragma unroll
        for (int t = 0; t < 4; ++t) {
            const bf16* kp = &Ks[cur][(16 * t + n) * PADk + g * 8];
            short8 kf0 = *(const short8*)(kp);
            short8 kf1 = *(const short8*)(kp + 32);
            scv[t] = mfma_bf16(qf0, kf0, scv[t]);
            scv[t] = mfma_bf16(qf1, kf1, scv[t]);
        }
        __builtin_amdgcn_s_setprio(0);

        const int s0 = c * 64;
        #pragma unroll
        for (int r = 0; r < 4; ++r) {
            const int row = wave * 16 + g * 4 + r;
            const int nib = (int)((mcur[r] >> (4 * n)) & 15ull);
            float vals[4];
            #pragma unroll
            for (int t = 0; t < 4; ++t) {
                const int s = s0 + 4 * n + t;
                const bool ok = fix_r[r] || (s <= limit_r[r] && ((nib >> t) & 1));
                vals[t] = ok ? scv[t][r] : -3.0e38f;
            }
            float cm = fmaxf(fmaxf(vals[0], vals[1]), fmaxf(vals[2], vals[3]));
            cm = fmaxf(cm, __shfl_xor(cm, 1));
            cm = fmaxf(cm, __shfl_xor(cm, 2));
            cm = fmaxf(cm, __shfl_xor(cm, 4));
            cm = fmaxf(cm, __shfl_xor(cm, 8));
            const float mnew = fmaxf(m_run[r], cm);
            const float alpha = __expf(m_run[r] - mnew);
            float csum = 0.f;
            union PK { uint2 u; bf16 hb[4]; } pk;
            #pragma unroll
            for (int t = 0; t < 4; ++t) {
                const float p = (vals[t] < -1.0e37f) ? 0.f : __expf(vals[t] - mnew);
                csum += p;
                pk.hb[t] = __float2bfloat16(p);
            }
            *(uint2*)(&Pw[wave][(row & 15) * PADk + 4 * n]) = pk.u;
            csum += __shfl_xor(csum, 1);
            csum += __shfl_xor(csum, 2);
            csum += __shfl_xor(csum, 4);
            csum += __shfl_xor(csum, 8);
            l_run[r] = l_run[r] * alpha + csum;
            m_run[r] = mnew;
            #pragma unroll
            for (int t = 0; t < 4; ++t) oacc[t][r] *= alpha;
        }
        // no barrier: Pw is wave-private (ds dependency orders write->read)

        __builtin_amdgcn_s_setprio(1);
        #pragma unroll
        for (int sc2 = 0; sc2 < 2; ++sc2) {
            short8 pa = *(const short8*)(Pw[wave] + n * PADk + sc2 * 32 + g * 8);
            #pragma unroll
            for (int t = 0; t < 4; ++t) {
                short8 vb = *(const short8*)(&Vs[cur][(16 * t + n) * PADk + sc2 * 32 + g * 8]);
                oacc[t] = mfma_bf16(pa, vb, oacc[t]);
            }
        }
        __builtin_amdgcn_s_setprio(0);

        // stage chunk c+1 into the other buffer (vmcnt covered by compute)
        if (more) {
            const int nxt = cur ^ 1;
            *(uint4*)(&Ks[nxt][kofsA]) = kr0;
            *(uint4*)(&Ks[nxt][kofsB]) = kr1;
            *(uint4*)(&Vs[nxt][vofsA]) = vr0;
            *(uint4*)(&Vs[nxt][vofsB]) = vr1;
            #pragma unroll
            for (int r = 0; r < 4; ++r) { bcur[r] = bnxt[r]; mcur[r] = mnxt[r]; }
        }
        __syncthreads();   // single barrier per chunk
    }

    #pragma unroll
    for (int r = 0; r < 4; ++r) {
        const int l = l0 + wave * 16 + g * 4 + r;
        const float inv = 1.f / l_run[r];
        #pragma unroll
        for (int t = 0; t < 4; ++t) {
            const int d = 16 * t + n;
            o[((size_t)(b * Lc + l)) * DIMc + h * DHc + d] =
                __float2bfloat16(oacc[t][r] * inv);
        }
    }
}

// ---------------------------------------------------------------------------
extern "C" void kernel_launch(void* const* d_in, const int* in_sizes, int n_in,
                              void* d_out, int out_size, void* d_ws, size_t ws_size,
                              hipStream_t stream)
{
    (void)in_sizes; (void)n_in; (void)out_size; (void)ws_size;

    const float* q        = (const float*)d_in[0];
    const float* k        = (const float*)d_in[1];
    const float* v        = (const float*)d_in[2];
    const int*   mask     = (const int*)d_in[3];
    const float* pos_bias = (const float*)d_in[4];
    const float* Wq = (const float*)d_in[5];
    const float* bq = (const float*)d_in[6];
    const float* Wk = (const float*)d_in[7];
    const float* bk = (const float*)d_in[8];
    const float* Wv = (const float*)d_in[9];
    const float* bv = (const float*)d_in[10];
    const float* Wp = (const float*)d_in[11];
    const float* bp = (const float*)d_in[12];
    const int*   is_causal = (const int*)d_in[13];

    const size_t per = (size_t)Bc * NHc * Lc * DHc;   // 4M elems
    const size_t wsz = (size_t)DIMc * DIMc;           // 1M elems
    bf16* qh  = (bf16*)d_ws;
    bf16* kh  = qh + per;
    bf16* vt  = kh + per;
    bf16* oh  = vt + per;
    bf16* qb  = oh + per;
    bf16* kb  = qb + per;
    bf16* vb  = kb + per;
    bf16* wqt = vb + per;
    bf16* wkt = wqt + wsz;
    bf16* wvt = wkt + wsz;
    bf16* wpt = wvt + wsz;
    unsigned long long* mbits = (unsigned long long*)(wpt + wsz);
    int* rowany_g = (int*)(mbits + (size_t)Bc * Lc * 16);
    float* outp = (float*)d_out;

    dim3 bb(256);

    prep_kernel<<<7424, bb, 0, stream>>>(q, k, v, Wq, Wk, Wv, Wp, mask, is_causal,
                                         qb, kb, vb, wqt, wkt, wvt, wpt,
                                         mbits, rowany_g);

    dim3 gq(32, 8, 3);   // 4096/128 x 1024/128 x {q,k,v}
    gemm_qkv_kernel<<<gq, bb, 0, stream>>>(qb, kb, vb, wqt, wkt, wvt,
                                           bq, bk, bv, qh, kh, vt);

    flash_attn_kernel<<<(Bc * NHc) * (Lc / 64), bb, 0, stream>>>(
        qh, kh, vt, mbits, rowany_g, pos_bias, is_causal, oh);

    dim3 gg(32, 8);
    gemm_out_kernel<<<gg, bb, 0, stream>>>(oh, wpt, bp, outp);
}

// Round 5
// 550.614 us; speedup vs baseline: 1.0326x; 1.0326x over previous
//
#include <hip/hip_runtime.h>
#include <hip/hip_bf16.h>

typedef __hip_bfloat16 bf16;
typedef __attribute__((ext_vector_type(4))) float  floatx4;
typedef __attribute__((ext_vector_type(8))) short  short8;
typedef __attribute__((ext_vector_type(8))) __bf16 bf16x8;

constexpr int Bc = 4, Lc = 1024, Sc = 1024, DIMc = 1024, NHc = 16, DHc = 64;

// ---- MFMA dispatcher: works whether the builtin takes short8 or bf16x8 ----
template <typename V>
__device__ auto mfma_bf16_sel(V a, V b, floatx4 c, int)
    -> decltype(__builtin_amdgcn_mfma_f32_16x16x32_bf16(a, b, c, 0, 0, 0)) {
  return __builtin_amdgcn_mfma_f32_16x16x32_bf16(a, b, c, 0, 0, 0);
}
template <typename V>
__device__ floatx4 mfma_bf16_sel(V a, V b, floatx4 c, long) {
  bf16x8 a2 = __builtin_bit_cast(bf16x8, a);
  bf16x8 b2 = __builtin_bit_cast(bf16x8, b);
  return __builtin_amdgcn_mfma_f32_16x16x32_bf16(a2, b2, c, 0, 0, 0);
}
__device__ inline floatx4 mfma_bf16(short8 a, short8 b, floatx4 c) {
  return mfma_bf16_sel(a, b, c, 0);
}

// ---- async global->LDS (16B per lane, wave-uniform LDS base + lane*16) ----
__device__ inline void gload16(const bf16* g, bf16* l) {
  __builtin_amdgcn_global_load_lds(
      (const __attribute__((address_space(1))) unsigned int*)g,
      (__attribute__((address_space(3))) unsigned int*)l, 16, 0, 0);
}

// ---- DPP 16-lane rotate reductions (VALU; avoids ds_swizzle LDS traffic) ---
// row_ror:N ctrl = 0x120+N ; DPP "row" = 16 lanes = our n-group.
#define ROR16F(v, N)                                                     \
  __builtin_bit_cast(float, __builtin_amdgcn_update_dpp(                 \
      __builtin_bit_cast(int, v), __builtin_bit_cast(int, v),            \
      0x120 + (N), 0xF, 0xF, false))

__device__ inline float red_max16(float v) {
    v = fmaxf(v, ROR16F(v, 8));
    v = fmaxf(v, ROR16F(v, 4));
    v = fmaxf(v, ROR16F(v, 2));
    v = fmaxf(v, ROR16F(v, 1));
    return v;
}
__device__ inline float red_sum16(float v) {
    v += ROR16F(v, 8);
    v += ROR16F(v, 4);
    v += ROR16F(v, 2);
    v += ROR16F(v, 1);
    return v;
}

union U8 { uint4 u; bf16 h[8]; };

__device__ inline U8 load8cvt(const float* p) {
    float4 f0 = ((const float4*)p)[0];
    float4 f1 = ((const float4*)p)[1];
    U8 t;
    t.h[0] = __float2bfloat16(f0.x); t.h[1] = __float2bfloat16(f0.y);
    t.h[2] = __float2bfloat16(f0.z); t.h[3] = __float2bfloat16(f0.w);
    t.h[4] = __float2bfloat16(f1.x); t.h[5] = __float2bfloat16(f1.y);
    t.h[6] = __float2bfloat16(f1.z); t.h[7] = __float2bfloat16(f1.w);
    return t;
}

// ---------------------------------------------------------------------------
// Prep: blocks [0,6144): cast q,k,v fp32->bf16 (2048 elems/block).
//       blocks [6144,7168): transpose+cast weights into Wt[n][k] bf16.
//       blocks [7168,7424): bit-pack mask into mbits + rowany (causal-aware).
// ---------------------------------------------------------------------------
__global__ __launch_bounds__(256)
void prep_kernel(const float* __restrict__ q, const float* __restrict__ k,
                 const float* __restrict__ v,
                 const float* __restrict__ Wq, const float* __restrict__ Wk,
                 const float* __restrict__ Wv, const float* __restrict__ Wp,
                 const int* __restrict__ mask, const int* __restrict__ is_causal_p,
                 bf16* __restrict__ qb, bf16* __restrict__ kb,
                 bf16* __restrict__ vb,
                 bf16* __restrict__ wqt, bf16* __restrict__ wkt,
                 bf16* __restrict__ wvt, bf16* __restrict__ wpt,
                 unsigned long long* __restrict__ mbits,
                 int* __restrict__ rowany_g)
{
    __shared__ float tile[64][68];
    const int tid = threadIdx.x;
    int blk = blockIdx.x;

    if (blk < 6144) {
        const float* src = (blk < 2048) ? q : (blk < 4096) ? k : v;
        bf16*        dst = (blk < 2048) ? qb : (blk < 4096) ? kb : vb;
        const int off = (blk & 2047) * 2048 + tid * 8;
        U8 t = load8cvt(src + off);
        *(uint4*)(dst + off) = t.u;
    } else if (blk < 7168) {
        blk -= 6144;
        const int w  = blk >> 8, t2 = blk & 255;
        const float* W  = (w == 0) ? Wq : (w == 1) ? Wk : (w == 2) ? Wv : Wp;
        bf16*        Wt = (w == 0) ? wqt : (w == 1) ? wkt : (w == 2) ? wvt : wpt;
        const int tk = (t2 >> 4) << 6;   // k-tile base
        const int tn = (t2 & 15) << 6;   // n-tile base
        #pragma unroll
        for (int i = 0; i < 4; ++i) {
            const int r = (tid >> 4) + i * 16;   // 0..63 (k within tile)
            const int c = (tid & 15) << 2;       // 0..60 (n within tile)
            *(float4*)(&tile[r][c]) =
                *(const float4*)(W + (size_t)(tk + r) * DIMc + tn + c);
        }
        __syncthreads();
        #pragma unroll
        for (int j = 0; j < 2; ++j) {
            const int nn = tid >> 2;                  // 0..63
            const int kc = (tid & 3) + j * 4;         // 0..7
            U8 o;
            #pragma unroll
            for (int u = 0; u < 8; ++u)
                o.h[u] = __float2bfloat16(tile[kc * 8 + u][nn]);
            *(uint4*)(Wt + (size_t)(tn + nn) * DIMc + tk + kc * 8) = o.u;
        }
    } else {
        const int mb  = blk - 7168;          // 0..255
        const int rIb = tid >> 4;            // 0..15
        const int w   = tid & 15;            // 64-bit word within row
        const int row = mb * 16 + rIb;       // 0..4095  (b*1024 + l)
        const int l   = row & (Lc - 1);
        const bool causal = (is_causal_p[0] != 0);

        const int4* mr4 = (const int4*)(mask + (size_t)row * Sc + w * 64);
        unsigned long long bits = 0ull;
        #pragma unroll
        for (int i = 0; i < 16; ++i) {
            int4 m4 = mr4[i];
            unsigned long long nib =
                (unsigned long long)((m4.x != 0) | ((m4.y != 0) << 1) |
                                     ((m4.z != 0) << 2) | ((m4.w != 0) << 3));
            bits |= nib << (4 * i);
        }
        mbits[(size_t)row * 16 + w] = bits;

        const int limit = causal ? l : (Sc - 1);
        const int base  = w * 64;
        unsigned long long am;
        if (limit >= base + 63)  am = bits;
        else if (limit < base)   am = 0ull;
        else                     am = bits & ((2ull << (limit - base)) - 1ull);
        unsigned long long red = am;
        #pragma unroll
        for (int d2 = 1; d2 < 16; d2 <<= 1) red |= __shfl_xor(red, d2);
        if (w == 0) rowany_g[row] = (red != 0ull) ? 1 : 0;
    }
}

// ---------------------------------------------------------------------------
// m97-structure GEMM (B^T form): bf16 A and Bt, global_load_lds width-16
// staging into LINEAR LDS [128][64], BK=64, 4 waves 2x2, 4x4 MFMA per wave.
// Fused QKV via blockIdx.z. qh is pre-scaled by 0.125 (flash adds no scale).
// z<2 -> out[((b*NH+h)*L+l)*DH+d] ; z==2 -> out[((b*NH+h)*DH+d)*S+l]
// ---------------------------------------------------------------------------
__global__ __launch_bounds__(256)
void gemm_qkv_kernel(const bf16* __restrict__ qb, const bf16* __restrict__ kb,
                     const bf16* __restrict__ vb,
                     const bf16* __restrict__ wqt, const bf16* __restrict__ wkt,
                     const bf16* __restrict__ wvt,
                     const float* __restrict__ bq, const float* __restrict__ bk,
                     const float* __restrict__ bv,
                     bf16* __restrict__ qh, bf16* __restrict__ kh,
                     bf16* __restrict__ vt)
{
    __shared__ __align__(16) bf16 As[128 * 64];
    __shared__ __align__(16) bf16 Bs[128 * 64];

    const int z = blockIdx.z;
    const bf16*  A    = (z == 0) ? qb  : (z == 1) ? kb  : vb;
    const bf16*  Bt   = (z == 0) ? wqt : (z == 1) ? wkt : wvt;
    const float* bias = (z == 0) ? bq  : (z == 1) ? bk  : bv;
    bf16*        out  = (z == 0) ? qh  : (z == 1) ? kh  : vt;
    const float  scale = (z == 0) ? 0.125f : 1.0f;

    const int tid  = threadIdx.x;
    const int wave = tid >> 6;
    const int lane = tid & 63;
    const int n = lane & 15, g = lane >> 4;
    const int m0 = blockIdx.x * 128;
    const int n0 = blockIdx.y * 128;
    const int wq_m = (wave & 1) * 64, wq_n = (wave >> 1) * 64;

    const int lrow   = lane >> 3;     // 0..7
    const int lchunk = (lane & 7) * 8;

    floatx4 acc[4][4];
    #pragma unroll
    for (int a = 0; a < 4; ++a)
        #pragma unroll
        for (int b2 = 0; b2 < 4; ++b2)
            acc[a][b2] = (floatx4){0.f, 0.f, 0.f, 0.f};

    for (int k0 = 0; k0 < DIMc; k0 += 64) {
        #pragma unroll
        for (int j = 0; j < 4; ++j) {
            const int rbase = j * 32 + wave * 8;
            const int r = rbase + lrow;
            gload16(A  + (size_t)(m0 + r) * DIMc + k0 + lchunk, As + rbase * 64);
            gload16(Bt + (size_t)(n0 + r) * DIMc + k0 + lchunk, Bs + rbase * 64);
        }
        __syncthreads();
        #pragma unroll
        for (int ks = 0; ks < 2; ++ks) {
            short8 af[4], bf_[4];
            #pragma unroll
            for (int t = 0; t < 4; ++t) {
                af[t]  = *(const short8*)(&As[(wq_m + t * 16 + n) * 64 + ks * 32 + g * 8]);
                bf_[t] = *(const short8*)(&Bs[(wq_n + t * 16 + n) * 64 + ks * 32 + g * 8]);
            }
            #pragma unroll
            for (int tm = 0; tm < 4; ++tm)
                #pragma unroll
                for (int tn = 0; tn < 4; ++tn)
                    acc[tm][tn] = mfma_bf16(af[tm], bf_[tn], acc[tm][tn]);
        }
        __syncthreads();
    }

    // epilogue: C/D layout col = lane&15 (=n), row = g*4 + r
    #pragma unroll
    for (int tn = 0; tn < 4; ++tn) {
        const int col = n0 + wq_n + tn * 16 + n;
        const float bval = bias[col];
        #pragma unroll
        for (int tm = 0; tm < 4; ++tm) {
            #pragma unroll
            for (int r = 0; r < 4; ++r) {
                const int row = m0 + wq_m + tm * 16 + g * 4 + r;
                const float vv = (acc[tm][tn][r] + bval) * scale;
                const int bb = row >> 10, ll = row & (Lc - 1);
                const int hh = col >> 6,  dd = col & 63;
                size_t idx;
                if (z < 2) idx = (((size_t)(bb * NHc + hh) * Lc + ll) * DHc) + dd;
                else       idx = (((size_t)(bb * NHc + hh) * DHc + dd) * Sc) + ll;
                out[idx] = __float2bfloat16(vv);
            }
        }
    }
}

// ---------------------------------------------------------------------------
// Output-projection GEMM, m97 structure: A bf16, fp32 out, row-major.
// ---------------------------------------------------------------------------
__global__ __launch_bounds__(256)
void gemm_out_kernel(const bf16* __restrict__ A, const bf16* __restrict__ Bt,
                     const float* __restrict__ bias, float* __restrict__ out)
{
    __shared__ __align__(16) bf16 As[128 * 64];
    __shared__ __align__(16) bf16 Bs[128 * 64];

    const int tid  = threadIdx.x;
    const int wave = tid >> 6;
    const int lane = tid & 63;
    const int n = lane & 15, g = lane >> 4;
    const int m0 = blockIdx.x * 128;
    const int n0 = blockIdx.y * 128;
    const int wq_m = (wave & 1) * 64, wq_n = (wave >> 1) * 64;

    const int lrow   = lane >> 3;
    const int lchunk = (lane & 7) * 8;

    floatx4 acc[4][4];
    #pragma unroll
    for (int a = 0; a < 4; ++a)
        #pragma unroll
        for (int b2 = 0; b2 < 4; ++b2)
            acc[a][b2] = (floatx4){0.f, 0.f, 0.f, 0.f};

    for (int k0 = 0; k0 < DIMc; k0 += 64) {
        #pragma unroll
        for (int j = 0; j < 4; ++j) {
            const int rbase = j * 32 + wave * 8;
            const int r = rbase + lrow;
            gload16(A  + (size_t)(m0 + r) * DIMc + k0 + lchunk, As + rbase * 64);
            gload16(Bt + (size_t)(n0 + r) * DIMc + k0 + lchunk, Bs + rbase * 64);
        }
        __syncthreads();
        #pragma unroll
        for (int ks = 0; ks < 2; ++ks) {
            short8 af[4], bf_[4];
            #pragma unroll
            for (int t = 0; t < 4; ++t) {
                af[t]  = *(const short8*)(&As[(wq_m + t * 16 + n) * 64 + ks * 32 + g * 8]);
                bf_[t] = *(const short8*)(&Bs[(wq_n + t * 16 + n) * 64 + ks * 32 + g * 8]);
            }
            #pragma unroll
            for (int tm = 0; tm < 4; ++tm)
                #pragma unroll
                for (int tn = 0; tn < 4; ++tn)
                    acc[tm][tn] = mfma_bf16(af[tm], bf_[tn], acc[tm][tn]);
        }
        __syncthreads();
    }

    #pragma unroll
    for (int tn = 0; tn < 4; ++tn) {
        const int col = n0 + wq_n + tn * 16 + n;
        const float bval = bias[col];
        #pragma unroll
        for (int tm = 0; tm < 4; ++tm) {
            #pragma unroll
            for (int r = 0; r < 4; ++r) {
                const int row = m0 + wq_m + tm * 16 + g * 4 + r;
                out[(size_t)row * DIMc + col] = acc[tm][tn][r] + bval;
            }
        }
    }
}

// ---------------------------------------------------------------------------
// Flash MFMA attention (R3 structure: 2 barriers/chunk, single K/V buffer,
// reg-prefetch one chunk ahead, 5 blocks/CU) with:
//  - Ks stride 66 (Rw=33 dwords): QK^T reads rows 4n+t -> start dword
//    4n+const mod 32 -> 2 lanes/bank (free). Writes r+4c -> free.
//  - Vs/Pw stride 72: V-read rows 16t+n -> 4n mod 32 (free); Pw rows n (free).
//  - DPP row_ror reductions (VALU) replace shfl_xor (ds_swizzle/LDS pipe).
//  - bias folded into QK^T accumulator init (qh pre-scaled by 0.125).
//  - s_setprio(1) around MFMA clusters; heavy-first dispatch.
// ---------------------------------------------------------------------------
constexpr int KPAD = 66;
constexpr int VPAD = 72;
constexpr int PPAD = 72;

__global__ __launch_bounds__(256)
void flash_attn_kernel(const bf16* __restrict__ qh, const bf16* __restrict__ kh,
                       const bf16* __restrict__ vt,
                       const unsigned long long* __restrict__ mbits,
                       const int* __restrict__ rowany_g,
                       const float* __restrict__ pos_bias,
                       const int* __restrict__ is_causal_p, bf16* __restrict__ o)
{
    __shared__ bf16 Ks[64 * KPAD];
    __shared__ bf16 Vs[64 * VPAD];
    __shared__ bf16 Pw[4][16 * PPAD];
    __shared__ int rowany[64];
    __shared__ int hasfix_s;

    const int tid  = threadIdx.x;
    const int lane = tid & 63;
    const int wave = tid >> 6;
    const int n = lane & 15;
    const int g = lane >> 4;

    // heavy-first: qt descending in dispatch order
    const int qt = 15 - (blockIdx.x >> 6);
    const int bh = blockIdx.x & 63;
    const int h  = bh & (NHc - 1);
    const int b  = bh >> 4;
    const int l0 = qt * 64;
    const bool causal = (is_causal_p[0] != 0);

    if (tid == 0) hasfix_s = 0;
    __syncthreads();
    if (tid < 64) {
        const int ra = rowany_g[(b << 10) + l0 + tid];
        rowany[tid] = ra;
        if (ra == 0) atomicOr(&hasfix_s, 1);
    }
    __syncthreads();
    const bool hasfix = (hasfix_s != 0);

    const int qrow_frag = l0 + wave * 16 + n;
    const bf16* qp = qh + ((size_t)bh * Lc + qrow_frag) * DHc;
    const short8 qf0 = *(const short8*)(qp + g * 8);
    const short8 qf1 = *(const short8*)(qp + 32 + g * 8);

    // staging addresses (chunk offset: K += c*4096 elems, V += c*64 elems)
    const int r0a = tid >> 3;            // 0..31
    const int c0  = (tid & 7) * 8;       // 0..56
    const int r0b = r0a + 32;            // 32..63
    const bf16* kb0p = kh + ((size_t)bh * Sc + r0a) * DHc + c0;
    const bf16* kb1p = kh + ((size_t)bh * Sc + r0b) * DHc + c0;
    const bf16* vb0p = vt + ((size_t)bh * DHc + r0a) * Sc + c0;
    const bf16* vb1p = vt + ((size_t)bh * DHc + r0b) * Sc + c0;
    bf16* ksw0 = Ks + r0a * KPAD + c0;
    bf16* ksw1 = Ks + r0b * KPAD + c0;
    bf16* vsw0 = Vs + r0a * VPAD + c0;
    bf16* vsw1 = Vs + r0b * VPAD + c0;

    // per-row bias / mask bases + row-constant predicates
    union F4 { float4 v; float f[4]; };
    const float* brow[4];
    const unsigned long long* mrow[4];
    int limit_r[4]; bool fix_r[4];
    #pragma unroll
    for (int r = 0; r < 4; ++r) {
        const int row = wave * 16 + g * 4 + r;
        const int l = l0 + row;
        brow[r] = pos_bias + ((size_t)bh * Lc + l) * Sc + 4 * n;
        mrow[r] = mbits + ((size_t)(b << 10) + l) * 16;
        limit_r[r] = causal ? l : (Sc - 1);
        fix_r[r] = (rowany[row] == 0);
    }

    floatx4 oacc[4];
    #pragma unroll
    for (int t = 0; t < 4; ++t) oacc[t] = (floatx4){0.f, 0.f, 0.f, 0.f};
    float m_run[4], l_run[4];
    #pragma unroll
    for (int r = 0; r < 4; ++r) { m_run[r] = -3.0e38f; l_run[r] = 0.f; }

    int nchunk = Sc / 64;
    if (causal && !hasfix) nchunk = qt + 1;

    // prologue: prefetch chunk 0
    uint4 kr0 = *(const uint4*)(kb0p);
    uint4 kr1 = *(const uint4*)(kb1p);
    uint4 vr0 = *(const uint4*)(vb0p);
    uint4 vr1 = *(const uint4*)(vb1p);
    F4 bcur[4], bnxt[4];
    unsigned long long mcur[4], mnxt[4];
    #pragma unroll
    for (int r = 0; r < 4; ++r) {
        bcur[r].v = *(const float4*)(brow[r]);
        mcur[r]   = mrow[r][0];
    }

    for (int c = 0; c < nchunk; ++c) {
        __syncthreads();   // prev compute done with LDS; drains prefetched loads
        *(uint4*)ksw0 = kr0;  *(uint4*)ksw1 = kr1;
        *(uint4*)vsw0 = vr0;  *(uint4*)vsw1 = vr1;
        __syncthreads();   // staged tiles visible

        // prefetch chunk c+1 (overlaps compute; drained at next top barrier)
        if (c + 1 < nchunk) {
            const size_t ko = (size_t)(c + 1) * (64 * DHc);
            const int    vo = (c + 1) * 64;
            kr0 = *(const uint4*)(kb0p + ko);
            kr1 = *(const uint4*)(kb1p + ko);
            vr0 = *(const uint4*)(vb0p + vo);
            vr1 = *(const uint4*)(vb1p + vo);
            #pragma unroll
            for (int r = 0; r < 4; ++r) {
                bnxt[r].v = *(const float4*)(brow[r] + vo);
                mnxt[r]   = mrow[r][c + 1];
            }
        }

        const int s0 = c * 64;

        // QK^T with bias as accumulator init (qh pre-scaled by 0.125)
        floatx4 scv[4];
        #pragma unroll
        for (int t = 0; t < 4; ++t)
            scv[t] = (floatx4){bcur[0].f[t], bcur[1].f[t],
                               bcur[2].f[t], bcur[3].f[t]};
        __builtin_amdgcn_s_setprio(1);
        #pragma unroll
        for (int t = 0; t < 4; ++t) {
            const bf16* kp = Ks + (4 * n + t) * KPAD + g * 8;
            short8 kf0 = *(const short8*)(kp);
            short8 kf1 = *(const short8*)(kp + 32);
            scv[t] = mfma_bf16(qf0, kf0, scv[t]);
            scv[t] = mfma_bf16(qf1, kf1, scv[t]);
        }
        __builtin_amdgcn_s_setprio(0);

        #pragma unroll
        for (int r = 0; r < 4; ++r) {
            const int row = wave * 16 + g * 4 + r;
            const int nib = (int)((mcur[r] >> (4 * n)) & 15ull);
            float vals[4];
            #pragma unroll
            for (int t = 0; t < 4; ++t) {
                const int s = s0 + 4 * n + t;
                const bool ok = fix_r[r] || (s <= limit_r[r] && ((nib >> t) & 1));
                vals[t] = ok ? scv[t][r] : -3.0e38f;
            }
            float cm = fmaxf(fmaxf(vals[0], vals[1]), fmaxf(vals[2], vals[3]));
            cm = red_max16(cm);
            const float mnew = fmaxf(m_run[r], cm);
            const float alpha = __expf(m_run[r] - mnew);
            float csum = 0.f;
            union PK { uint2 u; bf16 hb[4]; } pk;
            #pragma unroll
            for (int t = 0; t < 4; ++t) {
                const float p = (vals[t] < -1.0e37f) ? 0.f : __expf(vals[t] - mnew);
                csum += p;
                pk.hb[t] = __float2bfloat16(p);
            }
            *(uint2*)(&Pw[wave][(row & 15) * PPAD + 4 * n]) = pk.u;
            csum = red_sum16(csum);
            l_run[r] = l_run[r] * alpha + csum;
            m_run[r] = mnew;
            #pragma unroll
            for (int t = 0; t < 4; ++t) oacc[t][r] *= alpha;
        }
        // no barrier: Pw is wave-private (ds dependency orders write->read)

        __builtin_amdgcn_s_setprio(1);
        #pragma unroll
        for (int sc2 = 0; sc2 < 2; ++sc2) {
            short8 pa = *(const short8*)(Pw[wave] + n * PPAD + sc2 * 32 + g * 8);
            #pragma unroll
            for (int t = 0; t < 4; ++t) {
                short8 vb = *(const short8*)(Vs + (16 * t + n) * VPAD + sc2 * 32 + g * 8);
                oacc[t] = mfma_bf16(pa, vb, oacc[t]);
            }
        }
        __builtin_amdgcn_s_setprio(0);

        // rotate bias/mask double-buffer
        #pragma unroll
        for (int r = 0; r < 4; ++r) { bcur[r] = bnxt[r]; mcur[r] = mnxt[r]; }
    }

    #pragma unroll
    for (int r = 0; r < 4; ++r) {
        const int l = l0 + wave * 16 + g * 4 + r;
        const float inv = 1.f / l_run[r];
        #pragma unroll
        for (int t = 0; t < 4; ++t) {
            const int d = 16 * t + n;
            o[((size_t)(b * Lc + l)) * DIMc + h * DHc + d] =
                __float2bfloat16(oacc[t][r] * inv);
        }
    }
}

// ---------------------------------------------------------------------------
extern "C" void kernel_launch(void* const* d_in, const int* in_sizes, int n_in,
                              void* d_out, int out_size, void* d_ws, size_t ws_size,
                              hipStream_t stream)
{
    (void)in_sizes; (void)n_in; (void)out_size; (void)ws_size;

    const float* q        = (const float*)d_in[0];
    const float* k        = (const float*)d_in[1];
    const float* v        = (const float*)d_in[2];
    const int*   mask     = (const int*)d_in[3];
    const float* pos_bias = (const float*)d_in[4];
    const float* Wq = (const float*)d_in[5];
    const float* bq = (const float*)d_in[6];
    const float* Wk = (const float*)d_in[7];
    const float* bk = (const float*)d_in[8];
    const float* Wv = (const float*)d_in[9];
    const float* bv = (const float*)d_in[10];
    const float* Wp = (const float*)d_in[11];
    const float* bp = (const float*)d_in[12];
    const int*   is_causal = (const int*)d_in[13];

    const size_t per = (size_t)Bc * NHc * Lc * DHc;   // 4M elems
    const size_t wsz = (size_t)DIMc * DIMc;           // 1M elems
    bf16* qh  = (bf16*)d_ws;
    bf16* kh  = qh + per;
    bf16* vt  = kh + per;
    bf16* oh  = vt + per;
    bf16* qb  = oh + per;
    bf16* kb  = qb + per;
    bf16* vb  = kb + per;
    bf16* wqt = vb + per;
    bf16* wkt = wqt + wsz;
    bf16* wvt = wkt + wsz;
    bf16* wpt = wvt + wsz;
    unsigned long long* mbits = (unsigned long long*)(wpt + wsz);
    int* rowany_g = (int*)(mbits + (size_t)Bc * Lc * 16);
    float* outp = (float*)d_out;

    dim3 bb(256);

    prep_kernel<<<7424, bb, 0, stream>>>(q, k, v, Wq, Wk, Wv, Wp, mask, is_causal,
                                         qb, kb, vb, wqt, wkt, wvt, wpt,
                                         mbits, rowany_g);

    dim3 gq(32, 8, 3);   // 4096/128 x 1024/128 x {q,k,v}
    gemm_qkv_kernel<<<gq, bb, 0, stream>>>(qb, kb, vb, wqt, wkt, wvt,
                                           bq, bk, bv, qh, kh, vt);

    flash_attn_kernel<<<(Bc * NHc) * (Lc / 64), bb, 0, stream>>>(
        qh, kh, vt, mbits, rowany_g, pos_bias, is_causal, oh);

    dim3 gg(32, 8);
    gemm_out_kernel<<<gg, bb, 0, stream>>>(oh, wpt, bp, outp);
}